// Round 5
// baseline (80.698 us; speedup 1.0000x reference)
//
#include <hip/hip_runtime.h>
#include <hip/hip_fp16.h>

#define K_TOP 10
#define PS 7
#define HD 4
#define QN 4096
#define TN 4
#define CN 64
#define HN 256
#define WN 256
#define K0 15
#define CH 16            // CN / HD
#define SP (PS * PS)     // 49
#define OUT_PER_Q (SP * CN)  // 3136
#define VIDT_BYTES (TN * CN * HN * WN * 2)  // 32 MB (f16)

typedef float f32x4 __attribute__((ext_vector_type(4)));

// ---- Pass 1: vid [T,C,H,W] f32 -> vidT [HD,T,H,W,16] f16 ----
// NT loads: vid f32 is dead after this pass; don't cache it.
__global__ __launch_bounds__(256) void transpose_f16_kernel(
    const float* __restrict__ vid, __half* __restrict__ vidT)
{
    __shared__ float s[CH][WN + 4];   // stride 260 floats -> <=2-way banks (free)
    const int b = blockIdx.x;
    const int h = b & 3;
    const int i = (b >> 2) & 255;
    const int t = b >> 10;
    const int tid = threadIdx.x;

    // 16 rows x 256 f32, float4-vectorized NT loads (4 iters/thread).
    for (int e = tid; e < CH * WN / 4; e += 256) {
        const int cc = e >> 6;        // 0..15
        const int j4 = (e & 63) * 4;  // 0..252
        const f32x4 v = __builtin_nontemporal_load(
            (const f32x4*)(vid + (size_t)(((t * CN) + (h * CH + cc)) * HN + i) * WN + j4));
        s[cc][j4 + 0] = v.x;
        s[cc][j4 + 1] = v.y;
        s[cc][j4 + 2] = v.z;
        s[cc][j4 + 3] = v.w;
    }
    __syncthreads();

    // Emit uint4 = 8 half channels at one position j; contiguous 16B stores.
    uint4* dst = (uint4*)(vidT + (size_t)(((h * TN + t) * HN + i) * WN) * CH);
    for (int e = tid; e < CH * WN / 8; e += 256) {   // 2 iters/thread
        const int c8 = e & 1;        // channel octet
        const int j  = e >> 1;       // position
        const int cb = c8 * 8;
        const __half2 p0 = __floats2half2_rn(s[cb + 0][j], s[cb + 1][j]);
        const __half2 p1 = __floats2half2_rn(s[cb + 2][j], s[cb + 3][j]);
        const __half2 p2 = __floats2half2_rn(s[cb + 4][j], s[cb + 5][j]);
        const __half2 p3 = __floats2half2_rn(s[cb + 6][j], s[cb + 7][j]);
        uint4 pk;
        __builtin_memcpy(&pk.x, &p0, 4);
        __builtin_memcpy(&pk.y, &p1, 4);
        __builtin_memcpy(&pk.z, &p2, 4);
        __builtin_memcpy(&pk.w, &p3, 4);
        dst[e] = pk;
    }
}

// ---- Pass 2: gather-weighted sum from f16 vidT, f32 accumulate ----
// 256 threads handle 2 q's. NT stores for out (never re-read) so L2 keeps vidT.
__global__ __launch_bounds__(256) void wpsum_gather_f16(
    const __half* __restrict__ vidT,
    const float* __restrict__ dists,
    const int*   __restrict__ inds,
    float*       __restrict__ out)
{
    __shared__ float s_w[2][HD][K_TOP];
    __shared__ int   s_base[2][HD][K_TOP];

    const int q0 = blockIdx.x * 2;
    const int tid = threadIdx.x;

    if (tid < 2 * HD * K_TOP) {
        const int sub  = tid / (HD * K_TOP);
        const int rest = tid - sub * (HD * K_TOP);
        const int h = rest / K_TOP;
        const int k = rest - h * K_TOP;
        const int idx = (h * QN + (q0 + sub)) * K0 + k;
        s_w[sub][h][k] = dists[idx];
        const int tt = inds[idx * 3 + 0];
        const int ii = inds[idx * 3 + 1];
        const int jj = inds[idx * 3 + 2];
        s_base[sub][h][k] = (((h * TN + tt) * HN + ii) * WN + jj) * CH;
    }
    __syncthreads();

    const int sub = tid >> 7;
    const int t2  = tid & 127;
    const int g   = t2 >> 1;     // position 0..63 (49 active)
    const int r   = t2 & 1;      // 8-channel chunk
    if (g >= SP) return;
    const int pi = g / PS;
    const int pj = g - pi * PS;
    const int poff = (pi * WN + pj) * CH + r * 8;

    float acc[HD][8];
    #pragma unroll
    for (int h = 0; h < HD; ++h)
        #pragma unroll
        for (int j = 0; j < 8; ++j) acc[h][j] = 0.f;

    #pragma unroll
    for (int h = 0; h < HD; ++h) {
        #pragma unroll
        for (int k = 0; k < K_TOP; ++k) {
            const float w = s_w[sub][h][k];
            const uint4 u = *(const uint4*)(vidT + s_base[sub][h][k] + poff);
            __half2 h0, h1, h2, h3;
            __builtin_memcpy(&h0, &u.x, 4);
            __builtin_memcpy(&h1, &u.y, 4);
            __builtin_memcpy(&h2, &u.z, 4);
            __builtin_memcpy(&h3, &u.w, 4);
            const float2 f0 = __half22float2(h0);
            const float2 f1 = __half22float2(h1);
            const float2 f2 = __half22float2(h2);
            const float2 f3 = __half22float2(h3);
            acc[h][0] = fmaf(w, f0.x, acc[h][0]);
            acc[h][1] = fmaf(w, f0.y, acc[h][1]);
            acc[h][2] = fmaf(w, f1.x, acc[h][2]);
            acc[h][3] = fmaf(w, f1.y, acc[h][3]);
            acc[h][4] = fmaf(w, f2.x, acc[h][4]);
            acc[h][5] = fmaf(w, f2.y, acc[h][5]);
            acc[h][6] = fmaf(w, f3.x, acc[h][6]);
            acc[h][7] = fmaf(w, f3.y, acc[h][7]);
        }
    }

    float* outq = out + (size_t)(q0 + sub) * OUT_PER_Q + g * CN;
    #pragma unroll
    for (int h = 0; h < HD; ++h) {
        const f32x4 v0 = {acc[h][0], acc[h][1], acc[h][2], acc[h][3]};
        const f32x4 v1 = {acc[h][4], acc[h][5], acc[h][6], acc[h][7]};
        __builtin_nontemporal_store(v0, (f32x4*)(outq + h * CH + r * 8));
        __builtin_nontemporal_store(v1, (f32x4*)(outq + h * CH + r * 8 + 4));
    }
}

// ---- Fallback (round-1 kernel) if workspace too small ----
__global__ __launch_bounds__(256) void wpsum_fallback(
    const float* __restrict__ vid,
    const float* __restrict__ dists,
    const int*   __restrict__ inds,
    float*       __restrict__ out)
{
    __shared__ float s_w[HD][K_TOP];
    __shared__ int   s_base[HD][K_TOP];
    __shared__ float s_acc[CN][SP + 1];

    const int q = blockIdx.x;
    const int t = threadIdx.x;

    if (t < HD * K_TOP) {
        const int h = t / K_TOP;
        const int k = t - h * K_TOP;
        const int idx = (h * QN + q) * K0 + k;
        s_w[h][k] = dists[idx];
        const int tt = inds[idx * 3 + 0];
        const int ii = inds[idx * 3 + 1];
        const int jj = inds[idx * 3 + 2];
        s_base[h][k] = ((tt * CN + h * CH) * HN + ii) * WN + jj;
    }
    __syncthreads();

    for (int e = t; e < OUT_PER_Q; e += 256) {
        const int c_all = e / SP;
        const int s     = e - c_all * SP;
        const int h  = c_all >> 4;
        const int c  = c_all & 15;
        const int pi = s / PS;
        const int pj = s - pi * PS;
        const int off = c * (HN * WN) + pi * WN + pj;
        float acc = 0.f;
        #pragma unroll
        for (int k = 0; k < K_TOP; ++k)
            acc = fmaf(s_w[h][k], vid[s_base[h][k] + off], acc);
        s_acc[c_all][s] = acc;
    }
    __syncthreads();

    float* outq = out + q * OUT_PER_Q;
    for (int e = t; e < OUT_PER_Q; e += 256) {
        outq[e] = s_acc[e & 63][e >> 6];
    }
}

extern "C" void kernel_launch(void* const* d_in, const int* in_sizes, int n_in,
                              void* d_out, int out_size, void* d_ws, size_t ws_size,
                              hipStream_t stream) {
    const float* vid   = (const float*)d_in[0];
    const float* dists = (const float*)d_in[1];
    const int*   inds  = (const int*)d_in[2];
    float* out = (float*)d_out;

    if (ws_size >= (size_t)VIDT_BYTES) {
        __half* vidT = (__half*)d_ws;
        transpose_f16_kernel<<<TN * HN * HD, 256, 0, stream>>>(vid, vidT);
        wpsum_gather_f16<<<QN / 2, 256, 0, stream>>>(vidT, dists, inds, out);
    } else {
        wpsum_fallback<<<QN, 256, 0, stream>>>(vid, dists, inds, out);
    }
}

// Round 6
// 75.510 us; speedup vs baseline: 1.0687x; 1.0687x over previous
//
#include <hip/hip_runtime.h>
#include <hip/hip_fp16.h>

#define K_TOP 10
#define PS 7
#define HD 4
#define QN 4096
#define TN 4
#define CN 64
#define HN 256
#define WN 256
#define K0 15
#define CH 16            // CN / HD
#define SP (PS * PS)     // 49
#define OUT_PER_Q (SP * CN)  // 3136
#define VIDT_BYTES (TN * CN * HN * WN * 2)  // 32 MB (f16)

typedef float f32x4 __attribute__((ext_vector_type(4)));

// ---- Pass 1: vid [T,C,H,W] f32 -> vidT [HD,T,H,W,16] f16 ----
// NT float4 loads (vid dead after this pass) + contiguous uint4 stores.
__global__ __launch_bounds__(256) void transpose_f16_kernel(
    const float* __restrict__ vid, __half* __restrict__ vidT)
{
    __shared__ float s[CH][WN + 4];   // stride 260 floats -> <=2-way banks (free)
    const int b = blockIdx.x;
    const int h = b & 3;
    const int i = (b >> 2) & 255;
    const int t = b >> 10;
    const int tid = threadIdx.x;

    // 16 rows x 256 f32, float4-vectorized NT loads (4 iters/thread).
    for (int e = tid; e < CH * WN / 4; e += 256) {
        const int cc = e >> 6;        // 0..15
        const int j4 = (e & 63) * 4;  // 0..252
        const f32x4 v = __builtin_nontemporal_load(
            (const f32x4*)(vid + (size_t)(((t * CN) + (h * CH + cc)) * HN + i) * WN + j4));
        s[cc][j4 + 0] = v.x;
        s[cc][j4 + 1] = v.y;
        s[cc][j4 + 2] = v.z;
        s[cc][j4 + 3] = v.w;
    }
    __syncthreads();

    // Emit uint4 = 8 half channels at one position j; contiguous 16B stores.
    uint4* dst = (uint4*)(vidT + (size_t)(((h * TN + t) * HN + i) * WN) * CH);
    for (int e = tid; e < CH * WN / 8; e += 256) {   // 2 iters/thread
        const int c8 = e & 1;        // channel octet
        const int j  = e >> 1;       // position
        const int cb = c8 * 8;
        const __half2 p0 = __floats2half2_rn(s[cb + 0][j], s[cb + 1][j]);
        const __half2 p1 = __floats2half2_rn(s[cb + 2][j], s[cb + 3][j]);
        const __half2 p2 = __floats2half2_rn(s[cb + 4][j], s[cb + 5][j]);
        const __half2 p3 = __floats2half2_rn(s[cb + 6][j], s[cb + 7][j]);
        uint4 pk;
        __builtin_memcpy(&pk.x, &p0, 4);
        __builtin_memcpy(&pk.y, &p1, 4);
        __builtin_memcpy(&pk.z, &p2, 4);
        __builtin_memcpy(&pk.w, &p3, 4);
        dst[e] = pk;
    }
}

// ---- Pass 2: gather-weighted sum from f16 vidT, f32 accumulate ----
// Round-4 version: plain float4 stores (NT stores regressed: VGPR 108,
// WRITE_SIZE +40% from partial-line HBM writes, no FETCH benefit).
__global__ __launch_bounds__(256) void wpsum_gather_f16(
    const __half* __restrict__ vidT,
    const float* __restrict__ dists,
    const int*   __restrict__ inds,
    float*       __restrict__ out)
{
    __shared__ float s_w[2][HD][K_TOP];
    __shared__ int   s_base[2][HD][K_TOP];

    const int q0 = blockIdx.x * 2;
    const int tid = threadIdx.x;

    if (tid < 2 * HD * K_TOP) {
        const int sub  = tid / (HD * K_TOP);
        const int rest = tid - sub * (HD * K_TOP);
        const int h = rest / K_TOP;
        const int k = rest - h * K_TOP;
        const int idx = (h * QN + (q0 + sub)) * K0 + k;
        s_w[sub][h][k] = dists[idx];
        const int tt = inds[idx * 3 + 0];
        const int ii = inds[idx * 3 + 1];
        const int jj = inds[idx * 3 + 2];
        s_base[sub][h][k] = (((h * TN + tt) * HN + ii) * WN + jj) * CH;
    }
    __syncthreads();

    const int sub = tid >> 7;
    const int t2  = tid & 127;
    const int g   = t2 >> 1;     // position 0..63 (49 active)
    const int r   = t2 & 1;      // 8-channel chunk
    if (g >= SP) return;
    const int pi = g / PS;
    const int pj = g - pi * PS;
    const int poff = (pi * WN + pj) * CH + r * 8;

    float acc[HD][8];
    #pragma unroll
    for (int h = 0; h < HD; ++h)
        #pragma unroll
        for (int j = 0; j < 8; ++j) acc[h][j] = 0.f;

    #pragma unroll
    for (int h = 0; h < HD; ++h) {
        #pragma unroll
        for (int k = 0; k < K_TOP; ++k) {
            const float w = s_w[sub][h][k];
            const uint4 u = *(const uint4*)(vidT + s_base[sub][h][k] + poff);
            __half2 h0, h1, h2, h3;
            __builtin_memcpy(&h0, &u.x, 4);
            __builtin_memcpy(&h1, &u.y, 4);
            __builtin_memcpy(&h2, &u.z, 4);
            __builtin_memcpy(&h3, &u.w, 4);
            const float2 f0 = __half22float2(h0);
            const float2 f1 = __half22float2(h1);
            const float2 f2 = __half22float2(h2);
            const float2 f3 = __half22float2(h3);
            acc[h][0] = fmaf(w, f0.x, acc[h][0]);
            acc[h][1] = fmaf(w, f0.y, acc[h][1]);
            acc[h][2] = fmaf(w, f1.x, acc[h][2]);
            acc[h][3] = fmaf(w, f1.y, acc[h][3]);
            acc[h][4] = fmaf(w, f2.x, acc[h][4]);
            acc[h][5] = fmaf(w, f2.y, acc[h][5]);
            acc[h][6] = fmaf(w, f3.x, acc[h][6]);
            acc[h][7] = fmaf(w, f3.y, acc[h][7]);
        }
    }

    float* outq = out + (size_t)(q0 + sub) * OUT_PER_Q + g * CN;
    #pragma unroll
    for (int h = 0; h < HD; ++h) {
        float4 v0 = {acc[h][0], acc[h][1], acc[h][2], acc[h][3]};
        float4 v1 = {acc[h][4], acc[h][5], acc[h][6], acc[h][7]};
        *(float4*)(outq + h * CH + r * 8)     = v0;
        *(float4*)(outq + h * CH + r * 8 + 4) = v1;
    }
}

// ---- Fallback (round-1 kernel) if workspace too small ----
__global__ __launch_bounds__(256) void wpsum_fallback(
    const float* __restrict__ vid,
    const float* __restrict__ dists,
    const int*   __restrict__ inds,
    float*       __restrict__ out)
{
    __shared__ float s_w[HD][K_TOP];
    __shared__ int   s_base[HD][K_TOP];
    __shared__ float s_acc[CN][SP + 1];

    const int q = blockIdx.x;
    const int t = threadIdx.x;

    if (t < HD * K_TOP) {
        const int h = t / K_TOP;
        const int k = t - h * K_TOP;
        const int idx = (h * QN + q) * K0 + k;
        s_w[h][k] = dists[idx];
        const int tt = inds[idx * 3 + 0];
        const int ii = inds[idx * 3 + 1];
        const int jj = inds[idx * 3 + 2];
        s_base[h][k] = ((tt * CN + h * CH) * HN + ii) * WN + jj;
    }
    __syncthreads();

    for (int e = t; e < OUT_PER_Q; e += 256) {
        const int c_all = e / SP;
        const int s     = e - c_all * SP;
        const int h  = c_all >> 4;
        const int c  = c_all & 15;
        const int pi = s / PS;
        const int pj = s - pi * PS;
        const int off = c * (HN * WN) + pi * WN + pj;
        float acc = 0.f;
        #pragma unroll
        for (int k = 0; k < K_TOP; ++k)
            acc = fmaf(s_w[h][k], vid[s_base[h][k] + off], acc);
        s_acc[c_all][s] = acc;
    }
    __syncthreads();

    float* outq = out + q * OUT_PER_Q;
    for (int e = t; e < OUT_PER_Q; e += 256) {
        outq[e] = s_acc[e & 63][e >> 6];
    }
}

extern "C" void kernel_launch(void* const* d_in, const int* in_sizes, int n_in,
                              void* d_out, int out_size, void* d_ws, size_t ws_size,
                              hipStream_t stream) {
    const float* vid   = (const float*)d_in[0];
    const float* dists = (const float*)d_in[1];
    const int*   inds  = (const int*)d_in[2];
    float* out = (float*)d_out;

    if (ws_size >= (size_t)VIDT_BYTES) {
        __half* vidT = (__half*)d_ws;
        transpose_f16_kernel<<<TN * HN * HD, 256, 0, stream>>>(vid, vidT);
        wpsum_gather_f16<<<QN / 2, 256, 0, stream>>>(vidT, dists, inds, out);
    } else {
        wpsum_fallback<<<QN, 256, 0, stream>>>(vid, dists, inds, out);
    }
}